// Round 1
// baseline (109.880 us; speedup 1.0000x reference)
//
#include <hip/hip_runtime.h>
#include <math.h>

// Problem constants (from reference): B=8, C=32, H=512, W=512, fp32.
#define SG_H 512
#define SG_W 512
#define SG_ROWS 4   // output rows per thread

__global__ __launch_bounds__(256) void sobel_grad_kernel(
    const float* __restrict__ in, float* __restrict__ out,
    const int* __restrict__ dirp, int planes)
{
    const int dir = *dirp;  // uniform scalar branch
    const int plane = blockIdx.y;
    const size_t base = (size_t)plane * SG_H * SG_W;
    const int c0 = threadIdx.x * 4;                                   // column of this thread's float4
    const int r0 = (blockIdx.x * blockDim.y + threadIdx.y) * SG_ROWS; // first output row

    const float* __restrict__ p = in + base;
    float* __restrict__ q = out + base;

    float A[6], Bv[6], Cv[6];  // rolling 3-row window, 6 columns (c0-1 .. c0+4)

    auto loadRow = [&](int r, float v[6]) {
        if (r < 0 || r >= SG_H) {
            #pragma unroll
            for (int i = 0; i < 6; ++i) v[i] = 0.f;
            return;
        }
        const size_t ro = (size_t)r * SG_W;
        const float4 m = *reinterpret_cast<const float4*>(p + ro + c0);
        v[1] = m.x; v[2] = m.y; v[3] = m.z; v[4] = m.w;
        v[0] = (c0 > 0)        ? p[ro + c0 - 1] : 0.f;
        v[5] = (c0 + 4 < SG_W) ? p[ro + c0 + 4] : 0.f;
    };

    loadRow(r0 - 1, A);
    loadRow(r0,     Bv);

    for (int rr = r0; rr < r0 + SG_ROWS; ++rr) {
        loadRow(rr + 1, Cv);

        // separable vertical passes over the 6-col strip
        float t1[6], t2[6];
        #pragma unroll
        for (int i = 0; i < 6; ++i) {
            t1[i] = A[i] + 2.f * Bv[i] + Cv[i];  // vertical [1,2,1]  -> feeds gx
            t2[i] = Cv[i] - A[i];                // vertical [-1,0,1] -> feeds gy
        }

        float res[4];
        #pragma unroll
        for (int k = 0; k < 4; ++k) {
            const float gx = t1[k + 2] - t1[k];                       // horizontal [-1,0,1]
            const float gy = t2[k] + 2.f * t2[k + 1] + t2[k + 2];     // horizontal [1,2,1]
            float v;
            if (dir < 0)      v = fabsf(gx);
            else if (dir > 0) v = fabsf(gy);
            else              v = sqrtf(gx * gx + gy * gy);           // already >= 0
            res[k] = v;
        }

        float4 o;
        o.x = res[0]; o.y = res[1]; o.z = res[2]; o.w = res[3];
        *reinterpret_cast<float4*>(q + (size_t)rr * SG_W + c0) = o;

        #pragma unroll
        for (int i = 0; i < 6; ++i) { A[i] = Bv[i]; Bv[i] = Cv[i]; }
    }
}

extern "C" void kernel_launch(void* const* d_in, const int* in_sizes, int n_in,
                              void* d_out, int out_size, void* d_ws, size_t ws_size,
                              hipStream_t stream) {
    const float* in  = (const float*)d_in[0];
    const int*   dir = (const int*)d_in[1];
    float*       out = (float*)d_out;

    const int planes = in_sizes[0] / (SG_H * SG_W);  // B*C = 256

    dim3 block(SG_W / 4 / 2 * 2, 2);     // 128 x 2 = 256 threads
    // each block: 128 threads cover one 512-wide row strip; 2 strips of 4 rows = 8 rows
    dim3 grid(SG_H / (SG_ROWS * 2), planes);  // 64 x 256

    sobel_grad_kernel<<<grid, block, 0, stream>>>(in, out, dir, planes);
}

// Round 3
// 92.915 us; speedup vs baseline: 1.1826x; 1.1826x over previous
//
#include <hip/hip_runtime.h>
#include <math.h>

// Problem constants (from reference): B=8, C=32, H=512, W=512, fp32.
#define SG_H 512
#define SG_W 512
#define SG_ROWS 8   // output rows per thread (rolling 3-row window: 10 loads / 8 rows)

typedef float floatx4 __attribute__((ext_vector_type(4)));  // native vector: OK for nontemporal builtins

__global__ __launch_bounds__(256) void sobel_grad_kernel(
    const float* __restrict__ in, float* __restrict__ out,
    const int* __restrict__ dirp, int planes)
{
    const int dir = *dirp;  // uniform scalar branch
    const int plane = blockIdx.y;
    const size_t base = (size_t)plane * SG_H * SG_W;
    const int c0 = threadIdx.x * 4;                                   // column of this thread's float4
    const int r0 = (blockIdx.x * blockDim.y + threadIdx.y) * SG_ROWS; // first output row

    const float* __restrict__ p = in + base;
    float* __restrict__ q = out + base;

    float A[6], Bv[6], Cv[6];  // rolling 3-row window, 6 columns (c0-1 .. c0+4)

    auto loadRow = [&](int r, float v[6]) {
        if (r < 0 || r >= SG_H) {
            #pragma unroll
            for (int i = 0; i < 6; ++i) v[i] = 0.f;
            return;
        }
        const size_t ro = (size_t)r * SG_W;
        const floatx4 m = *reinterpret_cast<const floatx4*>(p + ro + c0);
        v[1] = m.x; v[2] = m.y; v[3] = m.z; v[4] = m.w;
        v[0] = (c0 > 0)        ? p[ro + c0 - 1] : 0.f;   // neighbor line: L1/L2 hit
        v[5] = (c0 + 4 < SG_W) ? p[ro + c0 + 4] : 0.f;
    };

    loadRow(r0 - 1, A);
    loadRow(r0,     Bv);

    #pragma unroll
    for (int s = 0; s < SG_ROWS; ++s) {
        const int rr = r0 + s;
        loadRow(rr + 1, Cv);

        // separable vertical passes over the 6-col strip
        float t1[6], t2[6];
        #pragma unroll
        for (int i = 0; i < 6; ++i) {
            t1[i] = A[i] + 2.f * Bv[i] + Cv[i];  // vertical [1,2,1]  -> feeds gx
            t2[i] = Cv[i] - A[i];                // vertical [-1,0,1] -> feeds gy
        }

        float res[4];
        #pragma unroll
        for (int k = 0; k < 4; ++k) {
            const float gx = t1[k + 2] - t1[k];                       // horizontal [-1,0,1]
            const float gy = t2[k] + 2.f * t2[k + 1] + t2[k + 2];     // horizontal [1,2,1]
            float v;
            if (dir < 0)      v = fabsf(gx);
            else if (dir > 0) v = fabsf(gy);
            else              v = sqrtf(gx * gx + gy * gy);           // already >= 0
            res[k] = v;
        }

        floatx4 o;
        o.x = res[0]; o.y = res[1]; o.z = res[2]; o.w = res[3];
        __builtin_nontemporal_store(o, reinterpret_cast<floatx4*>(q + (size_t)rr * SG_W + c0));

        #pragma unroll
        for (int i = 0; i < 6; ++i) { A[i] = Bv[i]; Bv[i] = Cv[i]; }
    }
}

extern "C" void kernel_launch(void* const* d_in, const int* in_sizes, int n_in,
                              void* d_out, int out_size, void* d_ws, size_t ws_size,
                              hipStream_t stream) {
    const float* in  = (const float*)d_in[0];
    const int*   dir = (const int*)d_in[1];
    float*       out = (float*)d_out;

    const int planes = in_sizes[0] / (SG_H * SG_W);  // B*C = 256

    dim3 block(SG_W / 4, 2);                  // 128 x 2 = 256 threads
    dim3 grid(SG_H / (SG_ROWS * 2), planes);  // 32 x 256 = 8192 blocks

    sobel_grad_kernel<<<grid, block, 0, stream>>>(in, out, dir, planes);
}

// Round 4
// 89.087 us; speedup vs baseline: 1.2334x; 1.0430x over previous
//
#include <hip/hip_runtime.h>
#include <math.h>

// Problem constants (from reference): B=8, C=32, H=512, W=512, fp32.
#define SG_H 512
#define SG_W 512
#define SG_ROWS 16  // output rows per thread (rolling 3-row window: 18 loads / 16 rows)

typedef float floatx4 __attribute__((ext_vector_type(4)));  // native vector: OK for nontemporal builtins

__global__ __launch_bounds__(256) void sobel_grad_kernel(
    const float* __restrict__ in, float* __restrict__ out,
    const int* __restrict__ dirp, int planes)
{
    const int dir = *dirp;  // uniform scalar branch
    const int plane = blockIdx.y;
    const size_t base = (size_t)plane * SG_H * SG_W;
    const int c0 = threadIdx.x * 4;                                   // column of this thread's float4
    const int r0 = (blockIdx.x * blockDim.y + threadIdx.y) * SG_ROWS; // first output row

    const float* __restrict__ p = in + base;
    float* __restrict__ q = out + base;

    float A[6], Bv[6], Cv[6];  // rolling 3-row window, 6 columns (c0-1 .. c0+4)

    auto loadRow = [&](int r, float v[6]) {
        if (r < 0 || r >= SG_H) {
            #pragma unroll
            for (int i = 0; i < 6; ++i) v[i] = 0.f;
            return;
        }
        const size_t ro = (size_t)r * SG_W;
        const floatx4 m = *reinterpret_cast<const floatx4*>(p + ro + c0);
        v[1] = m.x; v[2] = m.y; v[3] = m.z; v[4] = m.w;
        v[0] = (c0 > 0)        ? p[ro + c0 - 1] : 0.f;   // neighbor line: L1/L2 hit
        v[5] = (c0 + 4 < SG_W) ? p[ro + c0 + 4] : 0.f;
    };

    loadRow(r0 - 1, A);
    loadRow(r0,     Bv);

    #pragma unroll
    for (int s = 0; s < SG_ROWS; ++s) {
        const int rr = r0 + s;
        loadRow(rr + 1, Cv);

        // separable vertical passes over the 6-col strip
        float t1[6], t2[6];
        #pragma unroll
        for (int i = 0; i < 6; ++i) {
            t1[i] = A[i] + 2.f * Bv[i] + Cv[i];  // vertical [1,2,1]  -> feeds gx
            t2[i] = Cv[i] - A[i];                // vertical [-1,0,1] -> feeds gy
        }

        float res[4];
        #pragma unroll
        for (int k = 0; k < 4; ++k) {
            const float gx = t1[k + 2] - t1[k];                       // horizontal [-1,0,1]
            const float gy = t2[k] + 2.f * t2[k + 1] + t2[k + 2];     // horizontal [1,2,1]
            float v;
            if (dir < 0)      v = fabsf(gx);
            else if (dir > 0) v = fabsf(gy);
            else              v = __builtin_amdgcn_sqrtf(gx * gx + gy * gy);  // HW approx sqrt, ~1 ULP; tol=0.42
            res[k] = v;
        }

        floatx4 o;
        o.x = res[0]; o.y = res[1]; o.z = res[2]; o.w = res[3];
        __builtin_nontemporal_store(o, reinterpret_cast<floatx4*>(q + (size_t)rr * SG_W + c0));

        #pragma unroll
        for (int i = 0; i < 6; ++i) { A[i] = Bv[i]; Bv[i] = Cv[i]; }
    }
}

extern "C" void kernel_launch(void* const* d_in, const int* in_sizes, int n_in,
                              void* d_out, int out_size, void* d_ws, size_t ws_size,
                              hipStream_t stream) {
    const float* in  = (const float*)d_in[0];
    const int*   dir = (const int*)d_in[1];
    float*       out = (float*)d_out;

    const int planes = in_sizes[0] / (SG_H * SG_W);  // B*C = 256

    dim3 block(SG_W / 4, 2);                  // 128 x 2 = 256 threads
    dim3 grid(SG_H / (SG_ROWS * 2), planes);  // 16 x 256 = 4096 blocks

    sobel_grad_kernel<<<grid, block, 0, stream>>>(in, out, dir, planes);
}

// Round 5
// 84.559 us; speedup vs baseline: 1.2994x; 1.0535x over previous
//
#include <hip/hip_runtime.h>
#include <math.h>

// Problem constants (from reference): B=8, C=32, H=512, W=512, fp32.
#define SG_H 512
#define SG_W 512
#define SG_ROWS 32  // output rows per thread (rolling 3-row window: 34 loads / 32 rows = 1.0625x)

typedef float floatx4 __attribute__((ext_vector_type(4)));  // native vector: OK for nontemporal builtins

__global__ __launch_bounds__(256) void sobel_grad_kernel(
    const float* __restrict__ in, float* __restrict__ out,
    const int* __restrict__ dirp, int planes)
{
    const int dir = *dirp;  // uniform scalar branch
    const int plane = blockIdx.y;
    const size_t base = (size_t)plane * SG_H * SG_W;
    const int c0 = threadIdx.x * 4;                                   // column of this thread's float4
    const int r0 = (blockIdx.x * blockDim.y + threadIdx.y) * SG_ROWS; // first output row
    const int lane = threadIdx.x & 63;                                // wave lane (128 is mult of 64)

    const float* __restrict__ p = in + base;
    float* __restrict__ q = out + base;

    float A[6], Bv[6], Cv[6];  // rolling 3-row window, 6 columns (c0-1 .. c0+4)

    // Halo via wave shuffle: lane-1's m.w is our left neighbor, lane+1's m.x is
    // our right neighbor. Only the 2 wave-boundary lanes touch memory (exec-masked).
    auto loadRow = [&](int r, float v[6]) {
        if (r < 0 || r >= SG_H) {
            #pragma unroll
            for (int i = 0; i < 6; ++i) v[i] = 0.f;
            return;
        }
        const size_t ro = (size_t)r * SG_W;
        const floatx4 m = *reinterpret_cast<const floatx4*>(p + ro + c0);
        v[1] = m.x; v[2] = m.y; v[3] = m.z; v[4] = m.w;
        float left  = __shfl_up(m.w, 1);
        float right = __shfl_down(m.x, 1);
        if (lane == 0)  left  = (c0 > 0)        ? p[ro + c0 - 1] : 0.f;
        if (lane == 63) right = (c0 + 4 < SG_W) ? p[ro + c0 + 4] : 0.f;
        v[0] = left; v[5] = right;
    };

    loadRow(r0 - 1, A);
    loadRow(r0,     Bv);

    #pragma unroll
    for (int s = 0; s < SG_ROWS; ++s) {
        const int rr = r0 + s;
        loadRow(rr + 1, Cv);

        // separable vertical passes over the 6-col strip
        float t1[6], t2[6];
        #pragma unroll
        for (int i = 0; i < 6; ++i) {
            t1[i] = A[i] + 2.f * Bv[i] + Cv[i];  // vertical [1,2,1]  -> feeds gx
            t2[i] = Cv[i] - A[i];                // vertical [-1,0,1] -> feeds gy
        }

        float res[4];
        #pragma unroll
        for (int k = 0; k < 4; ++k) {
            const float gx = t1[k + 2] - t1[k];                       // horizontal [-1,0,1]
            const float gy = t2[k] + 2.f * t2[k + 1] + t2[k + 2];     // horizontal [1,2,1]
            float v;
            if (dir < 0)      v = fabsf(gx);
            else if (dir > 0) v = fabsf(gy);
            else              v = __builtin_amdgcn_sqrtf(gx * gx + gy * gy);  // HW sqrt ~1 ULP; tol=0.42
            res[k] = v;
        }

        floatx4 o;
        o.x = res[0]; o.y = res[1]; o.z = res[2]; o.w = res[3];
        __builtin_nontemporal_store(o, reinterpret_cast<floatx4*>(q + (size_t)rr * SG_W + c0));

        #pragma unroll
        for (int i = 0; i < 6; ++i) { A[i] = Bv[i]; Bv[i] = Cv[i]; }
    }
}

extern "C" void kernel_launch(void* const* d_in, const int* in_sizes, int n_in,
                              void* d_out, int out_size, void* d_ws, size_t ws_size,
                              hipStream_t stream) {
    const float* in  = (const float*)d_in[0];
    const int*   dir = (const int*)d_in[1];
    float*       out = (float*)d_out;

    const int planes = in_sizes[0] / (SG_H * SG_W);  // B*C = 256

    dim3 block(SG_W / 4, 2);                  // 128 x 2 = 256 threads
    dim3 grid(SG_H / (SG_ROWS * 2), planes);  // 8 x 256 = 2048 blocks (8 blocks/CU exactly)

    sobel_grad_kernel<<<grid, block, 0, stream>>>(in, out, dir, planes);
}